// Round 1
// baseline (7157.392 us; speedup 1.0000x reference)
//
#include <hip/hip_runtime.h>

// GCN encoder: 3 layers of  out = Ddst^-1/2 * A * Dsrc^-1/2 * X * W + b
// N=100000, E=1600000, dims 128->128->128->64, all fp32.
//
// Strategy (round 0, correctness + baseline counters):
//  - degrees/norms once via fp32 HW atomics
//  - SpMM: edge-parallel gather+atomic-scatter (norm_src folded into gather)
//  - GEMM: LDS-staged fp32 vector GEMM, norm_dst folded into row staging, bias in epilogue
//  - layer 2 computes X@W2 BEFORE the SpMM (linear ops commute) -> 64-wide scatter

#define DK 128   // inner feature dim for all GEMMs

__device__ __forceinline__ void atomAdd(float* p, float v) {
    unsafeAtomicAdd(p, v);   // global_atomic_add_f32 (HW), device scope
}

__global__ __launch_bounds__(256) void deg_kernel(const int* __restrict__ src,
                                                  const int* __restrict__ dst,
                                                  float* __restrict__ deg_out,
                                                  float* __restrict__ deg_in, int E) {
    int e = blockIdx.x * blockDim.x + threadIdx.x;
    if (e < E) {
        atomAdd(&deg_out[src[e]], 1.0f);
        atomAdd(&deg_in[dst[e]], 1.0f);
    }
}

__global__ __launch_bounds__(256) void norm_finish(float* __restrict__ a,
                                                   float* __restrict__ b, int n) {
    int i = blockIdx.x * blockDim.x + threadIdx.x;
    if (i < n) {
        a[i] = 1.0f / sqrtf(fmaxf(a[i], 1.0f));
        b[i] = 1.0f / sqrtf(fmaxf(b[i], 1.0f));
    }
}

// agg[dst] += x[src] * norm_src[src], D floats per edge, float4 per thread
template <int D>
__global__ __launch_bounds__(256) void spmm_kernel(const float* __restrict__ x,
                                                   const float* __restrict__ nsrc,
                                                   const int* __restrict__ src,
                                                   const int* __restrict__ dst,
                                                   float* __restrict__ agg, int E) {
    constexpr int CH = D / 4;
    long long tid = (long long)blockIdx.x * blockDim.x + threadIdx.x;
    if (tid >= (long long)E * CH) return;
    int e = (int)(tid / CH);
    int c = (int)(tid % CH);
    int s = src[e];
    int d = dst[e];
    float ns = nsrc[s];
    const float4 v = *(const float4*)(x + (long long)s * D + c * 4);
    float* o = agg + (long long)d * D + c * 4;
    atomAdd(o + 0, v.x * ns);
    atomAdd(o + 1, v.y * ns);
    atomAdd(o + 2, v.z * ns);
    atomAdd(o + 3, v.w * ns);
}

// Y[n, C] = (X[n, 128] * rowscale?) @ W[128, C] + bias?
template <int C, bool SCALE, bool BIAS>
__global__ __launch_bounds__(512) void gemm_kernel(const float* __restrict__ X,
                                                   const float* __restrict__ W,
                                                   const float* __restrict__ bias,
                                                   const float* __restrict__ rowscale,
                                                   float* __restrict__ Y, int n) {
    constexpr int K = DK;
    constexpr int BM = 128;
    constexpr int KP = K + 4;          // 528B rows, 16B aligned
    constexpr int COLT = C / 4;        // threads across cols (32 or 16)
    constexpr int ROWT = 512 / COLT;   // thread rows (16 or 32)
    constexpr int RPT = BM / ROWT;     // rows per thread (8 or 4)

    __shared__ float sW[K][C];
    __shared__ float sX[BM][KP];

    const int tid = threadIdx.x;
    const int row0 = blockIdx.x * BM;

    // stage W (full)
    for (int i = tid; i < K * C / 4; i += 512) {
        float4 w = ((const float4*)W)[i];
        int k = i / (C / 4);
        int cc = i % (C / 4);
        *(float4*)&sW[k][cc * 4] = w;
    }
    // stage X tile (coalesced), fold row scale
    for (int i = tid; i < BM * (K / 4); i += 512) {
        int r = i / (K / 4);
        int kc = i % (K / 4);
        int gr = row0 + r;
        float4 v = make_float4(0.f, 0.f, 0.f, 0.f);
        if (gr < n) {
            v = *(const float4*)(X + (size_t)gr * K + kc * 4);
            if (SCALE) {
                float s = rowscale[gr];
                v.x *= s; v.y *= s; v.z *= s; v.w *= s;
            }
        }
        *(float4*)&sX[r][kc * 4] = v;
    }
    __syncthreads();

    const int tc = tid % COLT;
    const int tr = tid / COLT;
    const int c0 = tc * 4;
    const int r0 = tr * RPT;

    float acc[RPT][4];
#pragma unroll
    for (int i = 0; i < RPT; ++i)
#pragma unroll
        for (int j = 0; j < 4; ++j) acc[i][j] = 0.f;

    for (int k = 0; k < K; k += 4) {
        float wv[4][4];
#pragma unroll
        for (int j = 0; j < 4; ++j) {
            float4 t = *(const float4*)&sW[k + j][c0];
            wv[j][0] = t.x; wv[j][1] = t.y; wv[j][2] = t.z; wv[j][3] = t.w;
        }
#pragma unroll
        for (int i = 0; i < RPT; ++i) {
            float4 xv = *(const float4*)&sX[r0 + i][k];
#pragma unroll
            for (int j = 0; j < 4; ++j) {
                acc[i][j] += xv.x * wv[0][j] + xv.y * wv[1][j] +
                             xv.z * wv[2][j] + xv.w * wv[3][j];
            }
        }
    }

    float bv[4] = {0.f, 0.f, 0.f, 0.f};
    if (BIAS) {
        float4 t = ((const float4*)bias)[tc];
        bv[0] = t.x; bv[1] = t.y; bv[2] = t.z; bv[3] = t.w;
    }
#pragma unroll
    for (int i = 0; i < RPT; ++i) {
        int gr = row0 + r0 + i;
        if (gr < n) {
            float4 o = make_float4(acc[i][0] + bv[0], acc[i][1] + bv[1],
                                   acc[i][2] + bv[2], acc[i][3] + bv[3]);
            *(float4*)(Y + (size_t)gr * C + c0) = o;
        }
    }
}

// out[i, 0..63] = agg[i, 0..63] * ndst[i] + bias
__global__ __launch_bounds__(256) void scale_bias_kernel(const float* __restrict__ agg,
                                                         const float* __restrict__ ndst,
                                                         const float* __restrict__ bias,
                                                         float* __restrict__ out, int n) {
    int tid = blockIdx.x * blockDim.x + threadIdx.x;
    if (tid < n * 16) {
        int r = tid / 16;
        int c4 = tid % 16;
        float s = ndst[r];
        float4 v = *(const float4*)(agg + (size_t)r * 64 + c4 * 4);
        float4 b = ((const float4*)bias)[c4];
        float4 o = make_float4(v.x * s + b.x, v.y * s + b.y,
                               v.z * s + b.z, v.w * s + b.w);
        *(float4*)(out + (size_t)r * 64 + c4 * 4) = o;
    }
}

static inline int cdiv(long long a, long long b) { return (int)((a + b - 1) / b); }

extern "C" void kernel_launch(void* const* d_in, const int* in_sizes, int n_in,
                              void* d_out, int out_size, void* d_ws, size_t ws_size,
                              hipStream_t stream) {
    const float* feat = (const float*)d_in[0];
    const float* W0   = (const float*)d_in[1];
    const float* b0   = (const float*)d_in[2];
    const float* W1   = (const float*)d_in[3];
    const float* b1   = (const float*)d_in[4];
    const float* W2   = (const float*)d_in[5];
    const float* b2   = (const float*)d_in[6];
    const int*   src  = (const int*)d_in[7];
    const int*   dst  = (const int*)d_in[8];

    const int N = in_sizes[0] / DK;
    const int E = in_sizes[7];

    float* ws   = (float*)d_ws;
    float* nsrc = ws;                       // [N]
    float* ndst = ws + N;                   // [N]
    float* agg  = ws + 2 * (size_t)N;       // [N*128]
    float* h    = agg + (size_t)N * 128;    // [N*128]
    float* y2   = agg + (size_t)N * 64;     // layer-2 X@W2 lives in agg's top half

    // ---- degrees & norms (shared by all layers) ----
    hipMemsetAsync(nsrc, 0, 2 * (size_t)N * sizeof(float), stream);
    deg_kernel<<<cdiv(E, 256), 256, 0, stream>>>(src, dst, nsrc, ndst, E);
    norm_finish<<<cdiv(N, 256), 256, 0, stream>>>(nsrc, ndst, N);

    const int gemm_blocks = cdiv(N, 128);

    // ---- layer 0: agg = A*(feat*nsrc); h = (agg*ndst)@W0 + b0 ----
    hipMemsetAsync(agg, 0, (size_t)N * 128 * sizeof(float), stream);
    spmm_kernel<128><<<cdiv((long long)E * 32, 256), 256, 0, stream>>>(feat, nsrc, src, dst, agg, E);
    gemm_kernel<128, true, true><<<gemm_blocks, 512, 0, stream>>>(agg, W0, b0, ndst, h, N);

    // ---- layer 1 ----
    hipMemsetAsync(agg, 0, (size_t)N * 128 * sizeof(float), stream);
    spmm_kernel<128><<<cdiv((long long)E * 32, 256), 256, 0, stream>>>(h, nsrc, src, dst, agg, E);
    gemm_kernel<128, true, true><<<gemm_blocks, 512, 0, stream>>>(agg, W1, b1, ndst, h, N);

    // ---- layer 2: y2 = h@W2; agg64 = A*(y2*nsrc); out = agg64*ndst + b2 ----
    gemm_kernel<64, false, false><<<gemm_blocks, 512, 0, stream>>>(h, W2, nullptr, nullptr, y2, N);
    hipMemsetAsync(agg, 0, (size_t)N * 64 * sizeof(float), stream);
    spmm_kernel<64><<<cdiv((long long)E * 16, 256), 256, 0, stream>>>(y2, nsrc, src, dst, agg, E);
    scale_bias_kernel<<<cdiv((long long)N * 16, 256), 256, 0, stream>>>(agg, ndst, b2, (float*)d_out, N);
}

// Round 2
// 909.313 us; speedup vs baseline: 7.8712x; 7.8712x over previous
//
#include <hip/hip_runtime.h>

// GCN encoder: 3 layers of  out = Ddst^-1/2 * A * Dsrc^-1/2 * X * W + b
// N=100000, E=1600000, dims 128->128->128->64, all fp32.
//
// Round 1: replace edge-parallel atomic scatter (76 G atomics/s bound, 2700us
// per layer) with per-call CSR-by-dst build + per-node register-accumulate
// gather (no atomics in hot path, write-once rows).
//  - degrees via int atomics, norms once, reused by all layers
//  - single-block prefix scan -> row_ptr + cursor array
//  - cursor-scatter of src indices -> eidx (CSR adjacency)
//  - SpMM: 32 threads/node (float4 x 32 = 128 floats), serial edge loop,
//    nsrc folded into gather
//  - GEMM unchanged from round 0 (not yet the bottleneck)
//  - layer 2 computes X@W2 BEFORE the SpMM -> 64-wide gather

#define DK 128

// ---------- degree count (int atomics) ----------
__global__ __launch_bounds__(256) void deg_kernel(const int* __restrict__ src,
                                                  const int* __restrict__ dst,
                                                  int* __restrict__ deg_out,
                                                  int* __restrict__ deg_in, int E) {
    int e = blockIdx.x * blockDim.x + threadIdx.x;
    if (e < E) {
        atomicAdd(&deg_out[src[e]], 1);
        atomicAdd(&deg_in[dst[e]], 1);
    }
}

__global__ __launch_bounds__(256) void norm_kernel(const int* __restrict__ deg_out,
                                                   const int* __restrict__ deg_in,
                                                   float* __restrict__ nsrc,
                                                   float* __restrict__ ndst, int n) {
    int i = blockIdx.x * blockDim.x + threadIdx.x;
    if (i < n) {
        nsrc[i] = rsqrtf(fmaxf((float)deg_out[i], 1.0f));
        ndst[i] = rsqrtf(fmaxf((float)deg_in[i], 1.0f));
    }
}

// ---------- single-block prefix scan: row_ptr[i+1]=incl, cur[i]=excl ----------
__global__ __launch_bounds__(1024) void scan_kernel(const int* __restrict__ deg,
                                                    int* __restrict__ rp,
                                                    int* __restrict__ cur, int n) {
    __shared__ int wsum[16];
    __shared__ int s_carry;
    const int tid = threadIdx.x;
    if (tid == 0) { s_carry = 0; rp[0] = 0; }
    __syncthreads();
    for (int base = 0; base < n; base += 1024) {
        int i = base + tid;
        int v = (i < n) ? deg[i] : 0;
        int lane = tid & 63;
        int wv = tid >> 6;
        int sc = v;
#pragma unroll
        for (int off = 1; off < 64; off <<= 1) {
            int t = __shfl_up(sc, off, 64);
            if (lane >= off) sc += t;
        }
        if (lane == 63) wsum[wv] = sc;
        __syncthreads();
        if (wv == 0) {
            int t = (lane < 16) ? wsum[lane] : 0;
#pragma unroll
            for (int off = 1; off < 16; off <<= 1) {
                int u = __shfl_up(t, off, 64);
                if (lane >= off) t += u;
            }
            if (lane < 16) wsum[lane] = t;
        }
        __syncthreads();
        int blockoff = (wv > 0) ? wsum[wv - 1] : 0;
        int incl = sc + blockoff + s_carry;
        if (i < n) { rp[i + 1] = incl; cur[i] = incl - v; }
        __syncthreads();
        if (tid == 1023) s_carry += wsum[15];
        __syncthreads();
    }
}

// ---------- scatter src indices into CSR slots ----------
__global__ __launch_bounds__(256) void fill_kernel(const int* __restrict__ src,
                                                   const int* __restrict__ dst,
                                                   int* __restrict__ cur,
                                                   int* __restrict__ eidx, int E) {
    int e = blockIdx.x * blockDim.x + threadIdx.x;
    if (e < E) {
        int pos = atomicAdd(&cur[dst[e]], 1);
        eidx[pos] = src[e];
    }
}

// ---------- SpMM gather: agg[r,:] = sum_{e in in(r)} x[src_e,:]*nsrc[src_e] ----------
template <int D>
__global__ __launch_bounds__(256) void spmm_gather(const float* __restrict__ x,
                                                   const float* __restrict__ nsrc,
                                                   const int* __restrict__ eidx,
                                                   const int* __restrict__ rp,
                                                   float* __restrict__ agg, int n) {
    constexpr int TPN = D / 4;        // threads per node (32 or 16)
    constexpr int NPB = 256 / TPN;    // nodes per block (8 or 16)
    const int node = blockIdx.x * NPB + threadIdx.x / TPN;
    const int lane = threadIdx.x % TPN;
    if (node >= n) return;
    const int beg = rp[node];
    const int end = rp[node + 1];
    float4 acc = make_float4(0.f, 0.f, 0.f, 0.f);
#pragma unroll 4
    for (int e = beg; e < end; ++e) {
        int s = eidx[e];
        float ns = nsrc[s];
        float4 v = *(const float4*)(x + (size_t)s * D + lane * 4);
        acc.x += v.x * ns;
        acc.y += v.y * ns;
        acc.z += v.z * ns;
        acc.w += v.w * ns;
    }
    *(float4*)(agg + (size_t)node * D + lane * 4) = acc;
}

// ---------- dense GEMM: Y = (X * rowscale?) @ W + bias? ----------
template <int C, bool SCALE, bool BIAS>
__global__ __launch_bounds__(512) void gemm_kernel(const float* __restrict__ X,
                                                   const float* __restrict__ W,
                                                   const float* __restrict__ bias,
                                                   const float* __restrict__ rowscale,
                                                   float* __restrict__ Y, int n) {
    constexpr int K = DK;
    constexpr int BM = 128;
    constexpr int KP = K + 4;
    constexpr int COLT = C / 4;
    constexpr int ROWT = 512 / COLT;
    constexpr int RPT = BM / ROWT;

    __shared__ float sW[K][C];
    __shared__ float sX[BM][KP];

    const int tid = threadIdx.x;
    const int row0 = blockIdx.x * BM;

    for (int i = tid; i < K * C / 4; i += 512) {
        float4 w = ((const float4*)W)[i];
        int k = i / (C / 4);
        int cc = i % (C / 4);
        *(float4*)&sW[k][cc * 4] = w;
    }
    for (int i = tid; i < BM * (K / 4); i += 512) {
        int r = i / (K / 4);
        int kc = i % (K / 4);
        int gr = row0 + r;
        float4 v = make_float4(0.f, 0.f, 0.f, 0.f);
        if (gr < n) {
            v = *(const float4*)(X + (size_t)gr * K + kc * 4);
            if (SCALE) {
                float s = rowscale[gr];
                v.x *= s; v.y *= s; v.z *= s; v.w *= s;
            }
        }
        *(float4*)&sX[r][kc * 4] = v;
    }
    __syncthreads();

    const int tc = tid % COLT;
    const int tr = tid / COLT;
    const int c0 = tc * 4;
    const int r0 = tr * RPT;

    float acc[RPT][4];
#pragma unroll
    for (int i = 0; i < RPT; ++i)
#pragma unroll
        for (int j = 0; j < 4; ++j) acc[i][j] = 0.f;

    for (int k = 0; k < K; k += 4) {
        float wv[4][4];
#pragma unroll
        for (int j = 0; j < 4; ++j) {
            float4 t = *(const float4*)&sW[k + j][c0];
            wv[j][0] = t.x; wv[j][1] = t.y; wv[j][2] = t.z; wv[j][3] = t.w;
        }
#pragma unroll
        for (int i = 0; i < RPT; ++i) {
            float4 xv = *(const float4*)&sX[r0 + i][k];
#pragma unroll
            for (int j = 0; j < 4; ++j) {
                acc[i][j] += xv.x * wv[0][j] + xv.y * wv[1][j] +
                             xv.z * wv[2][j] + xv.w * wv[3][j];
            }
        }
    }

    float bv[4] = {0.f, 0.f, 0.f, 0.f};
    if (BIAS) {
        float4 t = ((const float4*)bias)[tc];
        bv[0] = t.x; bv[1] = t.y; bv[2] = t.z; bv[3] = t.w;
    }
#pragma unroll
    for (int i = 0; i < RPT; ++i) {
        int gr = row0 + r0 + i;
        if (gr < n) {
            float4 o = make_float4(acc[i][0] + bv[0], acc[i][1] + bv[1],
                                   acc[i][2] + bv[2], acc[i][3] + bv[3]);
            *(float4*)(Y + (size_t)gr * C + c0) = o;
        }
    }
}

// ---------- out = agg64 * ndst + b2 ----------
__global__ __launch_bounds__(256) void scale_bias_kernel(const float* __restrict__ agg,
                                                         const float* __restrict__ ndst,
                                                         const float* __restrict__ bias,
                                                         float* __restrict__ out, int n) {
    int tid = blockIdx.x * blockDim.x + threadIdx.x;
    if (tid < n * 16) {
        int r = tid / 16;
        int c4 = tid % 16;
        float s = ndst[r];
        float4 v = *(const float4*)(agg + (size_t)r * 64 + c4 * 4);
        float4 b = ((const float4*)bias)[c4];
        float4 o = make_float4(v.x * s + b.x, v.y * s + b.y,
                               v.z * s + b.z, v.w * s + b.w);
        *(float4*)(out + (size_t)r * 64 + c4 * 4) = o;
    }
}

static inline int cdiv(long long a, long long b) { return (int)((a + b - 1) / b); }

extern "C" void kernel_launch(void* const* d_in, const int* in_sizes, int n_in,
                              void* d_out, int out_size, void* d_ws, size_t ws_size,
                              hipStream_t stream) {
    const float* feat = (const float*)d_in[0];
    const float* W0   = (const float*)d_in[1];
    const float* b0   = (const float*)d_in[2];
    const float* W1   = (const float*)d_in[3];
    const float* b1   = (const float*)d_in[4];
    const float* W2   = (const float*)d_in[5];
    const float* b2   = (const float*)d_in[6];
    const int*   src  = (const int*)d_in[7];
    const int*   dst  = (const int*)d_in[8];

    const int N = in_sizes[0] / DK;
    const int E = in_sizes[7];

    // workspace layout (floats/ints, 4B each):
    //   nsrc[N] ndst[N] row_ptr[N+1] eidx[E] agg[N*128] h[N*128]
    //   deg_out/deg_in/cur alias into agg (only used before layer 0)
    float* ws      = (float*)d_ws;
    float* nsrc    = ws;
    float* ndst    = ws + N;
    int*   row_ptr = (int*)(ws + 2 * (size_t)N);
    int*   eidx    = row_ptr + (N + 1);
    float* agg     = (float*)(eidx + E + 1);          // [N*128]
    float* h       = agg + (size_t)N * 128;           // [N*128]
    int*   deg_out = (int*)agg;                       // temp alias
    int*   deg_in  = deg_out + N;
    int*   cur     = deg_in + N;
    float* y2      = agg;                             // layer-2 X@W2 (N*64)
    float* agg64   = agg + (size_t)N * 64;            // layer-2 gather output

    // ---- CSR build + norms ----
    hipMemsetAsync(deg_out, 0, 2 * (size_t)N * sizeof(int), stream);
    deg_kernel<<<cdiv(E, 256), 256, 0, stream>>>(src, dst, deg_out, deg_in, E);
    norm_kernel<<<cdiv(N, 256), 256, 0, stream>>>(deg_out, deg_in, nsrc, ndst, N);
    scan_kernel<<<1, 1024, 0, stream>>>(deg_in, row_ptr, cur, N);
    fill_kernel<<<cdiv(E, 256), 256, 0, stream>>>(src, dst, cur, eidx, E);

    const int gemm_blocks = cdiv(N, 128);

    // ---- layer 0 ----
    spmm_gather<128><<<cdiv(N, 8), 256, 0, stream>>>(feat, nsrc, eidx, row_ptr, agg, N);
    gemm_kernel<128, true, true><<<gemm_blocks, 512, 0, stream>>>(agg, W0, b0, ndst, h, N);

    // ---- layer 1 ----
    spmm_gather<128><<<cdiv(N, 8), 256, 0, stream>>>(h, nsrc, eidx, row_ptr, agg, N);
    gemm_kernel<128, true, true><<<gemm_blocks, 512, 0, stream>>>(agg, W1, b1, ndst, h, N);

    // ---- layer 2: y2 = h@W2; agg64 = gather(y2); out = agg64*ndst + b2 ----
    gemm_kernel<64, false, false><<<gemm_blocks, 512, 0, stream>>>(h, W2, nullptr, nullptr, y2, N);
    spmm_gather<64><<<cdiv(N, 16), 256, 0, stream>>>(y2, nsrc, eidx, row_ptr, agg64, N);
    scale_bias_kernel<<<cdiv((long long)N * 16, 256), 256, 0, stream>>>(agg64, ndst, b2, (float*)d_out, N);
}

// Round 3
// 805.589 us; speedup vs baseline: 8.8847x; 1.1288x over previous
//
#include <hip/hip_runtime.h>

// GCN encoder: 3 layers of  out = Ddst^-1/2 * A * Dsrc^-1/2 * X * W + b
// N=100000, E=1600000, dims 128->128->128->64, all fp32.
//
// Round 2:
//  - parallel 3-phase prefix scan for CSR row_ptr (was serial single-block)
//  - all norm scalings folded into producer epilogues:
//      h0' = nsrc*( (ndst*agg0)@W0 + b0 )   [gemm OSCALE]
//      h1  =       (ndst*agg1)@W1 + b1
//      y2' = nsrc*( h1@W2 )                 [gemm OSCALE]
//      out = ndst*agg2 + b2                 [fused in final spmm epilogue]
//  - spmm gather with TPN=D/8: two independent float4 loads per lane per edge
//    (2x memory-level parallelism; round-1 profile showed latency-bound, not BW)

#define DK 128

// ---------- degree count (int atomics) ----------
__global__ __launch_bounds__(256) void deg_kernel(const int* __restrict__ src,
                                                  const int* __restrict__ dst,
                                                  int* __restrict__ deg_out,
                                                  int* __restrict__ deg_in, int E) {
    int e = blockIdx.x * blockDim.x + threadIdx.x;
    if (e < E) {
        atomicAdd(&deg_out[src[e]], 1);
        atomicAdd(&deg_in[dst[e]], 1);
    }
}

__global__ __launch_bounds__(256) void norm_kernel(const int* __restrict__ deg_out,
                                                   const int* __restrict__ deg_in,
                                                   float* __restrict__ nsrc,
                                                   float* __restrict__ ndst, int n) {
    int i = blockIdx.x * blockDim.x + threadIdx.x;
    if (i < n) {
        nsrc[i] = rsqrtf(fmaxf((float)deg_out[i], 1.0f));
        ndst[i] = rsqrtf(fmaxf((float)deg_in[i], 1.0f));
    }
}

// ---------- phase A: per-chunk (2048 elems) local inclusive scan ----------
__global__ __launch_bounds__(256) void scanA(const int* __restrict__ deg,
                                             int* __restrict__ rp,
                                             int* __restrict__ csum, int n) {
    __shared__ int wsum[4];
    const int tid = threadIdx.x;
    const int base = blockIdx.x * 2048 + tid * 8;
    int v[8];
    int s = 0;
#pragma unroll
    for (int j = 0; j < 8; ++j) {
        int i = base + j;
        v[j] = (i < n) ? deg[i] : 0;
        s += v[j];
    }
    int run = 0;
#pragma unroll
    for (int j = 0; j < 8; ++j) { run += v[j]; v[j] = run; }   // thread-local inclusive
    const int lane = tid & 63;
    const int w = tid >> 6;
    int sc = s;
#pragma unroll
    for (int off = 1; off < 64; off <<= 1) {
        int t = __shfl_up(sc, off, 64);
        if (lane >= off) sc += t;
    }
    if (lane == 63) wsum[w] = sc;
    __syncthreads();
    int woff = 0;
    for (int k = 0; k < w; ++k) woff += wsum[k];
    const int texcl = woff + sc - s;   // exclusive offset of this thread within chunk
#pragma unroll
    for (int j = 0; j < 8; ++j) {
        int i = base + j;
        if (i < n) rp[i + 1] = texcl + v[j];
    }
    if (tid == 0) csum[blockIdx.x] = wsum[0] + wsum[1] + wsum[2] + wsum[3];
}

// ---------- phase B: scan chunk sums (G <= 256) ----------
__global__ __launch_bounds__(256) void scanB(const int* __restrict__ csum,
                                             int* __restrict__ coffs, int g) {
    __shared__ int wsum[4];
    const int tid = threadIdx.x;
    int s = (tid < g) ? csum[tid] : 0;
    const int lane = tid & 63;
    const int w = tid >> 6;
    int sc = s;
#pragma unroll
    for (int off = 1; off < 64; off <<= 1) {
        int t = __shfl_up(sc, off, 64);
        if (lane >= off) sc += t;
    }
    if (lane == 63) wsum[w] = sc;
    __syncthreads();
    int woff = 0;
    for (int k = 0; k < w; ++k) woff += wsum[k];
    if (tid < g) coffs[tid] = woff + sc - s;   // exclusive
}

// ---------- phase C: add chunk offsets, derive cursor ----------
__global__ __launch_bounds__(256) void scanC(const int* __restrict__ deg,
                                             const int* __restrict__ coffs,
                                             int* __restrict__ rp,
                                             int* __restrict__ cur, int n) {
    const int tid = threadIdx.x;
    const int base = blockIdx.x * 2048 + tid * 8;
    const int add = coffs[blockIdx.x];
#pragma unroll
    for (int j = 0; j < 8; ++j) {
        int i = base + j;
        if (i < n) {
            int r = rp[i + 1] + add;
            rp[i + 1] = r;
            cur[i] = r - deg[i];
        }
    }
    if (blockIdx.x == 0 && tid == 0) rp[0] = 0;
}

// ---------- scatter src indices into CSR slots ----------
__global__ __launch_bounds__(256) void fill_kernel(const int* __restrict__ src,
                                                   const int* __restrict__ dst,
                                                   int* __restrict__ cur,
                                                   int* __restrict__ eidx, int E) {
    int e = blockIdx.x * blockDim.x + threadIdx.x;
    if (e < E) {
        int pos = atomicAdd(&cur[dst[e]], 1);
        eidx[pos] = src[e];
    }
}

// ---------- SpMM gather ----------
// agg[r,:] = sum_{e in in(r)} x[src_e,:] * (NSRC ? nsrc[src_e] : 1)
// FINAL: out[r,:] = agg[r,:]*ndst[r] + bias
template <int D, bool NSRC, bool FINAL>
__global__ __launch_bounds__(256) void spmm_gather(const float* __restrict__ x,
                                                   const float* __restrict__ nsrc,
                                                   const int* __restrict__ eidx,
                                                   const int* __restrict__ rp,
                                                   const float* __restrict__ ndst,
                                                   const float* __restrict__ bias,
                                                   float* __restrict__ out, int n) {
    constexpr int TPN = D / 8;        // lanes per node (16 or 8)
    constexpr int NPB = 256 / TPN;    // nodes per block (16 or 32)
    const int node = blockIdx.x * NPB + threadIdx.x / TPN;
    const int lane = threadIdx.x % TPN;
    if (node >= n) return;
    const int beg = rp[node];
    const int end = rp[node + 1];
    float4 a0 = make_float4(0.f, 0.f, 0.f, 0.f);
    float4 a1 = make_float4(0.f, 0.f, 0.f, 0.f);
#pragma unroll 4
    for (int e = beg; e < end; ++e) {
        int s = eidx[e];
        const float* row = x + (size_t)s * D + lane * 8;
        float4 v0 = *(const float4*)(row);
        float4 v1 = *(const float4*)(row + 4);
        if (NSRC) {
            float ns = nsrc[s];
            a0.x += v0.x * ns; a0.y += v0.y * ns; a0.z += v0.z * ns; a0.w += v0.w * ns;
            a1.x += v1.x * ns; a1.y += v1.y * ns; a1.z += v1.z * ns; a1.w += v1.w * ns;
        } else {
            a0.x += v0.x; a0.y += v0.y; a0.z += v0.z; a0.w += v0.w;
            a1.x += v1.x; a1.y += v1.y; a1.z += v1.z; a1.w += v1.w;
        }
    }
    if (FINAL) {
        float sd = ndst[node];
        float4 b0 = *(const float4*)(bias + lane * 8);
        float4 b1 = *(const float4*)(bias + lane * 8 + 4);
        a0.x = a0.x * sd + b0.x; a0.y = a0.y * sd + b0.y;
        a0.z = a0.z * sd + b0.z; a0.w = a0.w * sd + b0.w;
        a1.x = a1.x * sd + b1.x; a1.y = a1.y * sd + b1.y;
        a1.z = a1.z * sd + b1.z; a1.w = a1.w * sd + b1.w;
    }
    float* o = out + (size_t)node * D + lane * 8;
    *(float4*)(o) = a0;
    *(float4*)(o + 4) = a1;
}

// ---------- dense GEMM: Y = (X * iscale?) @ W ( + bias? ), rows scaled by oscale? ----------
template <int C, bool ISCALE, bool OSCALE, bool BIAS>
__global__ __launch_bounds__(512) void gemm_kernel(const float* __restrict__ X,
                                                   const float* __restrict__ W,
                                                   const float* __restrict__ bias,
                                                   const float* __restrict__ iscale,
                                                   const float* __restrict__ oscale,
                                                   float* __restrict__ Y, int n) {
    constexpr int K = DK;
    constexpr int BM = 128;
    constexpr int KP = K + 4;
    constexpr int COLT = C / 4;
    constexpr int ROWT = 512 / COLT;
    constexpr int RPT = BM / ROWT;

    __shared__ float sW[K][C];
    __shared__ float sX[BM][KP];

    const int tid = threadIdx.x;
    const int row0 = blockIdx.x * BM;

    for (int i = tid; i < K * C / 4; i += 512) {
        float4 w = ((const float4*)W)[i];
        int k = i / (C / 4);
        int cc = i % (C / 4);
        *(float4*)&sW[k][cc * 4] = w;
    }
    for (int i = tid; i < BM * (K / 4); i += 512) {
        int r = i / (K / 4);
        int kc = i % (K / 4);
        int gr = row0 + r;
        float4 v = make_float4(0.f, 0.f, 0.f, 0.f);
        if (gr < n) {
            v = *(const float4*)(X + (size_t)gr * K + kc * 4);
            if (ISCALE) {
                float s = iscale[gr];
                v.x *= s; v.y *= s; v.z *= s; v.w *= s;
            }
        }
        *(float4*)&sX[r][kc * 4] = v;
    }
    __syncthreads();

    const int tc = tid % COLT;
    const int tr = tid / COLT;
    const int c0 = tc * 4;
    const int r0 = tr * RPT;

    float acc[RPT][4];
#pragma unroll
    for (int i = 0; i < RPT; ++i)
#pragma unroll
        for (int j = 0; j < 4; ++j) acc[i][j] = 0.f;

    for (int k = 0; k < K; k += 4) {
        float wv[4][4];
#pragma unroll
        for (int j = 0; j < 4; ++j) {
            float4 t = *(const float4*)&sW[k + j][c0];
            wv[j][0] = t.x; wv[j][1] = t.y; wv[j][2] = t.z; wv[j][3] = t.w;
        }
#pragma unroll
        for (int i = 0; i < RPT; ++i) {
            float4 xv = *(const float4*)&sX[r0 + i][k];
#pragma unroll
            for (int j = 0; j < 4; ++j) {
                acc[i][j] += xv.x * wv[0][j] + xv.y * wv[1][j] +
                             xv.z * wv[2][j] + xv.w * wv[3][j];
            }
        }
    }

    float bv[4] = {0.f, 0.f, 0.f, 0.f};
    if (BIAS) {
        float4 t = ((const float4*)bias)[tc];
        bv[0] = t.x; bv[1] = t.y; bv[2] = t.z; bv[3] = t.w;
    }
#pragma unroll
    for (int i = 0; i < RPT; ++i) {
        int gr = row0 + r0 + i;
        if (gr < n) {
            float os = OSCALE ? oscale[gr] : 1.0f;
            float4 o = make_float4((acc[i][0] + bv[0]) * os, (acc[i][1] + bv[1]) * os,
                                   (acc[i][2] + bv[2]) * os, (acc[i][3] + bv[3]) * os);
            *(float4*)(Y + (size_t)gr * C + c0) = o;
        }
    }
}

static inline int cdiv(long long a, long long b) { return (int)((a + b - 1) / b); }

extern "C" void kernel_launch(void* const* d_in, const int* in_sizes, int n_in,
                              void* d_out, int out_size, void* d_ws, size_t ws_size,
                              hipStream_t stream) {
    const float* feat = (const float*)d_in[0];
    const float* W0   = (const float*)d_in[1];
    const float* b0   = (const float*)d_in[2];
    const float* W1   = (const float*)d_in[3];
    const float* b1   = (const float*)d_in[4];
    const float* W2   = (const float*)d_in[5];
    const float* b2   = (const float*)d_in[6];
    const int*   src  = (const int*)d_in[7];
    const int*   dst  = (const int*)d_in[8];

    const int N = in_sizes[0] / DK;
    const int E = in_sizes[7];

    // workspace layout (4B units):
    //   nsrc[N] ndst[N] rp[N+1] csum[256] coffs[256] eidx[E] agg[N*128] h[N*128]
    //   deg_out/deg_in/cur alias agg (dead once layer 0 starts)
    float* ws      = (float*)d_ws;
    float* nsrc    = ws;
    float* ndst    = ws + N;
    int*   rp      = (int*)(ws + 2 * (size_t)N);
    int*   csum    = rp + (N + 1);
    int*   coffs   = csum + 256;
    int*   eidx    = coffs + 256;
    size_t aoff    = (size_t)(3 * (size_t)N + 513 + E + 3) & ~(size_t)3;
    float* agg     = ws + aoff;                       // [N*128]
    float* h       = agg + (size_t)N * 128;           // [N*128]
    int*   deg_out = (int*)agg;                       // temp aliases
    int*   deg_in  = deg_out + N;
    int*   cur     = deg_in + N;
    float* y2      = agg;                             // layer-2 nsrc*(h@W2), N*64

    const int chunks = cdiv(N, 2048);

    // ---- CSR build + norms ----
    hipMemsetAsync(deg_out, 0, 2 * (size_t)N * sizeof(int), stream);
    deg_kernel<<<cdiv(E, 256), 256, 0, stream>>>(src, dst, deg_out, deg_in, E);
    norm_kernel<<<cdiv(N, 256), 256, 0, stream>>>(deg_out, deg_in, nsrc, ndst, N);
    scanA<<<chunks, 256, 0, stream>>>(deg_in, rp, csum, N);
    scanB<<<1, 256, 0, stream>>>(csum, coffs, chunks);
    scanC<<<chunks, 256, 0, stream>>>(deg_in, coffs, rp, cur, N);
    fill_kernel<<<cdiv(E, 256), 256, 0, stream>>>(src, dst, cur, eidx, E);

    const int gemm_blocks = cdiv(N, 128);

    // ---- layer 0: agg = A*(nsrc*feat); h = nsrc*((ndst*agg)@W0 + b0) ----
    spmm_gather<128, true, false><<<cdiv(N, 16), 256, 0, stream>>>(
        feat, nsrc, eidx, rp, nullptr, nullptr, agg, N);
    gemm_kernel<128, true, true, true><<<gemm_blocks, 512, 0, stream>>>(
        agg, W0, b0, ndst, nsrc, h, N);

    // ---- layer 1: agg = A*h; h = (ndst*agg)@W1 + b1 ----
    spmm_gather<128, false, false><<<cdiv(N, 16), 256, 0, stream>>>(
        h, nullptr, eidx, rp, nullptr, nullptr, agg, N);
    gemm_kernel<128, true, false, true><<<gemm_blocks, 512, 0, stream>>>(
        agg, W1, b1, ndst, nullptr, h, N);

    // ---- layer 2: y2 = nsrc*(h@W2); out = ndst*(A*y2) + b2 ----
    gemm_kernel<64, false, true, false><<<gemm_blocks, 512, 0, stream>>>(
        h, W2, nullptr, nullptr, nsrc, y2, N);
    spmm_gather<64, false, true><<<cdiv(N, 32), 256, 0, stream>>>(
        y2, nullptr, eidx, rp, ndst, b2, (float*)d_out, N);
}